// Round 2
// baseline (796.442 us; speedup 1.0000x reference)
//
#include <hip/hip_runtime.h>
#include <math.h>

#define HH    768   // hidden dim
#define QL    20    // query tokens
#define SS    512   // seq len
#define DD    492   // doc tokens (512-20)
#define NBATCH 16
#define NLAYER 13   // unique layers (all_layers[0]==all_layers[1])
#define NBINS 11
#define DSPLIT 4
#define ROWS_PER 123        // 492/4
#define HHALF 384           // 768/2

// Grid (13,16,4). Block 256 threads = 2 halves x 128.
// half h owns h-range [h*384, h*384+384); thread tt<123 owns doc row dc*123+tt.
// h-halves combine partial dots via LDS; per-dc partial histograms go to ws.
__global__ __launch_bounds__(256)
void sim_hist_kernel(const float* __restrict__ hs, float* __restrict__ counts) {
    const int l  = blockIdx.x;   // 0..12
    const int b  = blockIdx.y;   // 0..15
    const int dc = blockIdx.z;   // 0..3
    const float* __restrict__ base = hs + (size_t)(l * NBATCH + b) * SS * HH;

    const int t    = threadIdx.x;
    const int half = t >> 7;         // 0 or 1
    const int tt   = t & 127;
    const float* __restrict__ hb = base + half * HHALF;

    __shared__ float s_qn2[2 * QL * 8];     // [half][q][seg] partial q norms
    __shared__ float s_qn[QL];              // final q norms
    __shared__ float s_pd[ROWS_PER * 22];   // half-1 partial dots (+dn2), padded
    __shared__ int   s_hist[NBINS];

    if (t < NBINS) s_hist[t] = 0;

    // ---- q partial norms: per half, 20 rows x 8 segments of 48 ----
    if (tt < QL * 8) {
        const int qi = tt >> 3;
        const int sg = tt & 7;
        const float* qp = hb + qi * HH + sg * 48;
        float s = 0.f;
        #pragma unroll
        for (int j = 0; j < 48; j += 4) {
            float4 v = *reinterpret_cast<const float4*>(qp + j);
            s += v.x * v.x + v.y * v.y + v.z * v.z + v.w * v.w;
        }
        s_qn2[(half * QL + qi) * 8 + sg] = s;
    }

    // ---- main: partial dots over this half's 384 h ----
    float acc[QL];
    #pragma unroll
    for (int q = 0; q < QL; ++q) acc[q] = 0.f;
    float dn2 = 0.f;

    const bool active = (tt < ROWS_PER);
    if (active) {
        const int row = QL + dc * ROWS_PER + tt;
        const float* __restrict__ dp = hb + (size_t)row * HH;
        for (int h = 0; h < HHALF; h += 16) {
            float4 d0 = *reinterpret_cast<const float4*>(dp + h + 0);
            float4 d1 = *reinterpret_cast<const float4*>(dp + h + 4);
            float4 d2 = *reinterpret_cast<const float4*>(dp + h + 8);
            float4 d3 = *reinterpret_cast<const float4*>(dp + h + 12);
            dn2 += d0.x*d0.x + d0.y*d0.y + d0.z*d0.z + d0.w*d0.w
                 + d1.x*d1.x + d1.y*d1.y + d1.z*d1.z + d1.w*d1.w
                 + d2.x*d2.x + d2.y*d2.y + d2.z*d2.z + d2.w*d2.w
                 + d3.x*d3.x + d3.y*d3.y + d3.z*d3.z + d3.w*d3.w;
            #pragma unroll
            for (int q = 0; q < QL; ++q) {
                // wave-uniform -> SMEM scalar loads (SGPRs), free of VALU cost
                const float* qp = hb + q * HH + h;
                float4 q0 = *reinterpret_cast<const float4*>(qp + 0);
                float4 q1 = *reinterpret_cast<const float4*>(qp + 4);
                float4 q2 = *reinterpret_cast<const float4*>(qp + 8);
                float4 q3 = *reinterpret_cast<const float4*>(qp + 12);
                acc[q] += q0.x*d0.x + q0.y*d0.y + q0.z*d0.z + q0.w*d0.w
                        + q1.x*d1.x + q1.y*d1.y + q1.z*d1.z + q1.w*d1.w
                        + q2.x*d2.x + q2.y*d2.y + q2.z*d2.z + q2.w*d2.w
                        + q3.x*d3.x + q3.y*d3.y + q3.z*d3.z + q3.w*d3.w;
            }
        }
    }
    __syncthreads();

    // half 1 publishes partials; q norms finalized
    if (half == 1 && active) {
        #pragma unroll
        for (int q = 0; q < QL; ++q) s_pd[tt * 22 + q] = acc[q];
        s_pd[tt * 22 + QL] = dn2;
    }
    if (t < QL) {
        float s = 0.f;
        #pragma unroll
        for (int sg = 0; sg < 8; ++sg)
            s += s_qn2[t * 8 + sg] + s_qn2[(QL + t) * 8 + sg];
        s_qn[t] = sqrtf(s);
    }
    __syncthreads();

    int cnt[NBINS];
    #pragma unroll
    for (int k = 0; k < NBINS; ++k) cnt[k] = 0;

    if (half == 0 && active) {
        const float dn = sqrtf(dn2 + s_pd[tt * 22 + QL]);
        #pragma unroll
        for (int q = 0; q < QL; ++q) {
            float dot = acc[q] + s_pd[tt * 22 + q];
            float denom = fmaxf(s_qn[q] * dn, 1e-8f);
            float sim = dot / denom;
            int bin = (int)floorf((sim + 1.0f) * 5.5f);   // 11 bins over [-1,1)
            #pragma unroll
            for (int k = 0; k < NBINS; ++k) cnt[k] += (bin == k) ? 1 : 0;
        }
    }

    // wave shuffle reduce then LDS atomics (waves 2,3 are all-zero -> skipped)
    #pragma unroll
    for (int k = 0; k < NBINS; ++k) {
        int v = cnt[k];
        for (int off = 32; off > 0; off >>= 1) v += __shfl_down(v, off, 64);
        if ((t & 63) == 0 && v != 0) atomicAdd(&s_hist[k], v);
    }
    __syncthreads();
    if (t < NBINS) {
        counts[(((size_t)l * NBATCH + b) * DSPLIT + dc) * NBINS + t] = (float)s_hist[t];
    }
}

// One block per batch element: cls dot + histogram feature fold + biases.
__global__ __launch_bounds__(256)
void finalize_kernel(const float* __restrict__ hs,
                     const float* __restrict__ Wh,   // (5,11)
                     const float* __restrict__ bh,   // (5,)
                     const float* __restrict__ Wc,   // (1,838)
                     const float* __restrict__ bc,   // (1,)
                     const float* __restrict__ counts,
                     float* __restrict__ out) {
    const int b = blockIdx.x;
    const int t = threadIdx.x;
    float p = 0.f;

    // cls = hidden_states[12][b][0][:]
    const float* cls = hs + ((size_t)(12 * NBATCH + b)) * SS * HH;
    for (int j = t; j < HH; j += 256) p += cls[j] * Wc[j];

    // histogram features: 14 layers x 11 bins
    if (t < 14 * NBINS) {
        const int l  = t / NBINS;             // 0..13 (all_layers index)
        const int n  = t % NBINS;
        const int lp = (l == 0) ? 0 : l - 1;  // unique-layer index
        float hsum = 0.f;
        #pragma unroll
        for (int dc = 0; dc < DSPLIT; ++dc)
            hsum += counts[(((size_t)lp * NBATCH + b) * DSPLIT + dc) * NBINS + n];
        float hist = hsum * (1.0f / (float)(QL * DD));
        float coef = 0.f;
        #pragma unroll
        for (int o = 0; o < 5; ++o) coef += Wc[HH + l * 5 + o] * Wh[o * NBINS + n];
        p += hist * coef;
    }

    if (t == 0) {
        float s = bc[0];
        for (int l = 0; l < 14; ++l)
            for (int o = 0; o < 5; ++o) s += Wc[HH + l * 5 + o] * bh[o];
        p += s;
    }

    __shared__ float red[256];
    red[t] = p;
    __syncthreads();
    for (int off = 128; off > 0; off >>= 1) {
        if (t < off) red[t] += red[t + off];
        __syncthreads();
    }
    if (t == 0) out[b] = red[0];
}

extern "C" void kernel_launch(void* const* d_in, const int* in_sizes, int n_in,
                              void* d_out, int out_size, void* d_ws, size_t ws_size,
                              hipStream_t stream) {
    const float* hs = (const float*)d_in[0];
    const float* Wh = (const float*)d_in[1];
    const float* bh = (const float*)d_in[2];
    const float* Wc = (const float*)d_in[3];
    const float* bc = (const float*)d_in[4];
    float* counts = (float*)d_ws;          // 13*16*4*11 floats, each written once
    float* out    = (float*)d_out;         // (16,1) fp32

    dim3 grid(NLAYER, NBATCH, DSPLIT);
    sim_hist_kernel<<<grid, 256, 0, stream>>>(hs, counts);
    finalize_kernel<<<NBATCH, 256, 0, stream>>>(hs, Wh, bh, Wc, bc, counts, out);
}

// Round 3
// 529.952 us; speedup vs baseline: 1.5029x; 1.5029x over previous
//
#include <hip/hip_runtime.h>
#include <hip/hip_fp16.h>
#include <math.h>

#define HH    768   // hidden dim
#define QL    20    // query tokens
#define SS    512   // seq len
#define DD    492   // doc tokens (512-20)
#define NBATCH 16
#define NLAYER 13   // unique layers (all_layers[0]==all_layers[1])
#define NBINS 11
#define ZSPLIT 4
#define HCHUNK 192          // 768/4
#define ROWPAD 512          // padded row dim in spill
#define SPILL_STRIDE (21 * ROWPAD)   // 20 dots + dn2, per (l,b,z)

// ---------------- kernel 1: partial dots over one h-chunk ----------------
// Grid (13,16,4). 512 threads. t<492: doc row t, fp32 partial dots vs all 20 q
// (q loads are block-uniform -> scalar s_load broadcasts, zero VALU cost).
// t in [492,512): q-row norm partial for q=t-492. Partials spilled fp16/fp32.
__global__ __launch_bounds__(512, 4)
void partial_kernel(const float* __restrict__ hs,
                    __half* __restrict__ spill,
                    float* __restrict__ qn_part) {
    const int l = blockIdx.x;
    const int b = blockIdx.y;
    const int z = blockIdx.z;
    const float* __restrict__ base = hs + (size_t)(l * NBATCH + b) * SS * HH;
    const float* __restrict__ hb   = base + z * HCHUNK;   // block-uniform
    const int t = threadIdx.x;
    const int lbz = (l * NBATCH + b) * ZSPLIT + z;

    if (t < DD) {
        const float* __restrict__ dp = hb + (size_t)(QL + t) * HH;
        float acc[QL];
        #pragma unroll
        for (int q = 0; q < QL; ++q) acc[q] = 0.f;
        float dn2 = 0.f;

        for (int h = 0; h < HCHUNK; h += 16) {
            float4 d0 = *reinterpret_cast<const float4*>(dp + h + 0);
            float4 d1 = *reinterpret_cast<const float4*>(dp + h + 4);
            float4 d2 = *reinterpret_cast<const float4*>(dp + h + 8);
            float4 d3 = *reinterpret_cast<const float4*>(dp + h + 12);
            dn2 += d0.x*d0.x + d0.y*d0.y + d0.z*d0.z + d0.w*d0.w
                 + d1.x*d1.x + d1.y*d1.y + d1.z*d1.z + d1.w*d1.w
                 + d2.x*d2.x + d2.y*d2.y + d2.z*d2.z + d2.w*d2.w
                 + d3.x*d3.x + d3.y*d3.y + d3.z*d3.z + d3.w*d3.w;
            #pragma unroll
            for (int q = 0; q < QL; ++q) {
                // block-uniform address -> scalar loads through SMEM pipe
                const float* qp = hb + q * HH + h;
                float4 q0 = *reinterpret_cast<const float4*>(qp + 0);
                float4 q1 = *reinterpret_cast<const float4*>(qp + 4);
                float4 q2 = *reinterpret_cast<const float4*>(qp + 8);
                float4 q3 = *reinterpret_cast<const float4*>(qp + 12);
                acc[q] += q0.x*d0.x + q0.y*d0.y + q0.z*d0.z + q0.w*d0.w
                        + q1.x*d1.x + q1.y*d1.y + q1.z*d1.z + q1.w*d1.w
                        + q2.x*d2.x + q2.y*d2.y + q2.z*d2.z + q2.w*d2.w
                        + q3.x*d3.x + q3.y*d3.y + q3.z*d3.z + q3.w*d3.w;
            }
        }
        __half* sp = spill + (size_t)lbz * SPILL_STRIDE;
        #pragma unroll
        for (int q = 0; q < QL; ++q) sp[q * ROWPAD + t] = __float2half(acc[q]);
        sp[QL * ROWPAD + t] = __float2half(dn2);
    } else {
        const int qi = t - DD;   // 0..19
        if (qi < QL) {
            const float* qp = hb + (size_t)qi * HH;
            float s = 0.f;
            for (int h = 0; h < HCHUNK; h += 4) {
                float4 v = *reinterpret_cast<const float4*>(qp + h);
                s += v.x*v.x + v.y*v.y + v.z*v.z + v.w*v.w;
            }
            qn_part[lbz * 32 + qi] = s;
        }
    }
}

// ---------------- kernel 2: reduce z-partials, sims, histogram ----------------
// Grid (13,16). 512 threads, thread t = doc row t.
__global__ __launch_bounds__(512)
void hist_kernel(const __half* __restrict__ spill,
                 const float* __restrict__ qn_part,
                 float* __restrict__ counts) {
    const int l = blockIdx.x;
    const int b = blockIdx.y;
    const int t = threadIdx.x;
    const int lb = l * NBATCH + b;

    __shared__ float s_qn[QL];
    __shared__ int   s_hist[NBINS];
    if (t < NBINS) s_hist[t] = 0;
    if (t < QL) {
        float s = 0.f;
        #pragma unroll
        for (int z = 0; z < ZSPLIT; ++z) s += qn_part[(lb * ZSPLIT + z) * 32 + t];
        s_qn[t] = sqrtf(s);
    }
    __syncthreads();

    int cnt[NBINS];
    #pragma unroll
    for (int k = 0; k < NBINS; ++k) cnt[k] = 0;

    if (t < DD) {
        const __half* sp = spill + (size_t)(lb * ZSPLIT) * SPILL_STRIDE;
        float dn2 = 0.f;
        #pragma unroll
        for (int z = 0; z < ZSPLIT; ++z)
            dn2 += __half2float(sp[z * SPILL_STRIDE + QL * ROWPAD + t]);
        const float dn = sqrtf(dn2);
        #pragma unroll
        for (int q = 0; q < QL; ++q) {
            float dot = 0.f;
            #pragma unroll
            for (int z = 0; z < ZSPLIT; ++z)
                dot += __half2float(sp[z * SPILL_STRIDE + q * ROWPAD + t]);
            float denom = fmaxf(s_qn[q] * dn, 1e-8f);
            float sim = dot / denom;
            int bin = (int)floorf((sim + 1.0f) * 5.5f);   // 11 bins over [-1,1)
            #pragma unroll
            for (int k = 0; k < NBINS; ++k) cnt[k] += (bin == k) ? 1 : 0;
        }
    }

    #pragma unroll
    for (int k = 0; k < NBINS; ++k) {
        int v = cnt[k];
        for (int off = 32; off > 0; off >>= 1) v += __shfl_down(v, off, 64);
        if ((t & 63) == 0 && v != 0) atomicAdd(&s_hist[k], v);
    }
    __syncthreads();
    if (t < NBINS) counts[(size_t)lb * NBINS + t] = (float)s_hist[t];
}

// ---------------- kernel 3: cls dot + histogram fold + biases ----------------
__global__ __launch_bounds__(256)
void finalize_kernel(const float* __restrict__ hs,
                     const float* __restrict__ Wh,   // (5,11)
                     const float* __restrict__ bh,   // (5,)
                     const float* __restrict__ Wc,   // (1,838)
                     const float* __restrict__ bc,   // (1,)
                     const float* __restrict__ counts,
                     float* __restrict__ out) {
    const int b = blockIdx.x;
    const int t = threadIdx.x;
    float p = 0.f;

    const float* cls = hs + ((size_t)(12 * NBATCH + b)) * SS * HH;
    for (int j = t; j < HH; j += 256) p += cls[j] * Wc[j];

    if (t < 14 * NBINS) {
        const int l  = t / NBINS;             // 0..13 (all_layers index)
        const int n  = t % NBINS;
        const int lp = (l == 0) ? 0 : l - 1;  // unique-layer index
        float hist = counts[((size_t)lp * NBATCH + b) * NBINS + n] * (1.0f / (float)(QL * DD));
        float coef = 0.f;
        #pragma unroll
        for (int o = 0; o < 5; ++o) coef += Wc[HH + l * 5 + o] * Wh[o * NBINS + n];
        p += hist * coef;
    }

    if (t == 0) {
        float s = bc[0];
        for (int l = 0; l < 14; ++l)
            for (int o = 0; o < 5; ++o) s += Wc[HH + l * 5 + o] * bh[o];
        p += s;
    }

    __shared__ float red[256];
    red[t] = p;
    __syncthreads();
    for (int off = 128; off > 0; off >>= 1) {
        if (t < off) red[t] += red[t + off];
        __syncthreads();
    }
    if (t == 0) out[b] = red[0];
}

extern "C" void kernel_launch(void* const* d_in, const int* in_sizes, int n_in,
                              void* d_out, int out_size, void* d_ws, size_t ws_size,
                              hipStream_t stream) {
    const float* hs = (const float*)d_in[0];
    const float* Wh = (const float*)d_in[1];
    const float* bh = (const float*)d_in[2];
    const float* Wc = (const float*)d_in[3];
    const float* bc = (const float*)d_in[4];

    // ws layout: fp16 spill | fp32 qn partials | fp32 counts  (~18 MB total)
    const size_t spill_elems = (size_t)NLAYER * NBATCH * ZSPLIT * SPILL_STRIDE;
    __half* spill  = (__half*)d_ws;
    float* qn_part = (float*)((char*)d_ws + spill_elems * sizeof(__half));
    float* counts  = qn_part + (size_t)NLAYER * NBATCH * ZSPLIT * 32;
    float* out     = (float*)d_out;

    dim3 g1(NLAYER, NBATCH, ZSPLIT);
    partial_kernel<<<g1, 512, 0, stream>>>(hs, spill, qn_part);
    dim3 g2(NLAYER, NBATCH);
    hist_kernel<<<g2, 512, 0, stream>>>(spill, qn_part, counts);
    finalize_kernel<<<NBATCH, 256, 0, stream>>>(hs, Wh, bh, Wc, bc, counts, out);
}

// Round 4
// 470.515 us; speedup vs baseline: 1.6927x; 1.1263x over previous
//
#include <hip/hip_runtime.h>
#include <math.h>

#define HH    768
#define QL    20
#define SS    512
#define DD    492
#define NBATCH 16
#define NLAYER 13
#define NBINS 11
#define DSPLIT 4
#define BROWS 123          // real d-rows per block
#define BN    128          // padded d-rows
#define BK    64
#define QPAD  776          // sQ row length in bf16 (768 + 8 pad)
#define BPAD  72           // sB row length in bf16 (64 + 8 pad)

typedef __attribute__((ext_vector_type(8))) short bf16x8;
typedef __attribute__((ext_vector_type(4))) float f32x4;

__device__ inline unsigned int pk2bf(float a, float b) {
    unsigned int ua = __float_as_uint(a);
    unsigned int ub = __float_as_uint(b);
    ua = (ua + 0x7fffu + ((ua >> 16) & 1u)) >> 16;   // RNE truncate
    ub = (ub + 0x7fffu + ((ub >> 16) & 1u)) >> 16;
    return ua | (ub << 16);
}

// Grid (13,16,4), 256 threads (4 waves). Per block: C(20x123) = Q(20x768)·Dchunk^T
// via mfma_f32_16x16x32_bf16, fp32 norms, fused histogram. Partial counts -> ws.
__global__ __launch_bounds__(256, 2)
void gemm_hist_kernel(const float* __restrict__ hs, float* __restrict__ counts) {
    const int l = blockIdx.x, b = blockIdx.y, dc = blockIdx.z;
    const float* __restrict__ base = hs + (size_t)(l * NBATCH + b) * SS * HH;
    const int t = threadIdx.x;
    const int wave = t >> 6, lane = t & 63;
    const int quad = lane >> 4, m16 = lane & 15;

    __shared__ unsigned short sQ[32 * QPAD];   // 49.7 KB, A tiles (bf16)
    __shared__ unsigned short sB[BN * BPAD];   // 18.4 KB, B tile (bf16)
    __shared__ float s_qn2[QL], s_qn[QL];
    __shared__ float s_dn2[BN], s_dn[BN];
    __shared__ int   s_hist[NBINS];

    // ---- zero init (qn2/dn2/hist + sQ pad rows 20..31) ----
    if (t < QL) s_qn2[t] = 0.f;
    if (t < BN) s_dn2[t] = 0.f;
    if (t < NBINS) s_hist[t] = 0;
    for (int i = t; i < 12 * QPAD; i += 256) sQ[20 * QPAD + i] = 0;
    __syncthreads();

    // ---- stage Q rows 0..19 fp32->bf16, accumulate q norms in fp32 ----
    #pragma unroll
    for (int j = 0; j < 15; ++j) {
        int i = t + 256 * j;                 // 0..3839 over (20 rows x 192 float4)
        int r = i / 192, c4 = i - r * 192;
        float4 v = *reinterpret_cast<const float4*>(base + r * HH + c4 * 4);
        atomicAdd(&s_qn2[r], v.x * v.x + v.y * v.y + v.z * v.z + v.w * v.w);
        uint2 hw;
        hw.x = pk2bf(v.x, v.y);
        hw.y = pk2bf(v.z, v.w);
        *reinterpret_cast<uint2*>(&sQ[r * QPAD + c4 * 4]) = hw;
    }

    f32x4 acc[2][2] = {{{0,0,0,0},{0,0,0,0}},{{0,0,0,0},{0,0,0,0}}};
    float dnacc[8];
    #pragma unroll
    for (int j = 0; j < 8; ++j) dnacc[j] = 0.f;

    const int rowbase = t >> 4;     // staging row = rowbase + 16j
    const int kf = t & 15;          // staging float4-column within BK

    for (int kt = 0; kt < HH / BK; ++kt) {
        const int kbase = kt * BK;
        __syncthreads();   // sB write-after-read (and first-iter sQ visibility)
        #pragma unroll
        for (int j = 0; j < 8; ++j) {
            int row = rowbase + 16 * j;
            int grow = QL + dc * BROWS + (row < BROWS ? row : BROWS - 1); // clamp pad
            float4 v = *reinterpret_cast<const float4*>(base + (size_t)grow * HH + kbase + kf * 4);
            dnacc[j] += v.x * v.x + v.y * v.y + v.z * v.z + v.w * v.w;
            uint2 hw;
            hw.x = pk2bf(v.x, v.y);
            hw.y = pk2bf(v.z, v.w);
            *reinterpret_cast<uint2*>(&sB[row * BPAD + kf * 4]) = hw;
        }
        __syncthreads();   // sB read-after-write
        #pragma unroll
        for (int ks = 0; ks < BK; ks += 32) {
            const int ka = kbase + ks + quad * 8;
            const int kb = ks + quad * 8;
            bf16x8 a0 = *reinterpret_cast<const bf16x8*>(&sQ[m16 * QPAD + ka]);
            bf16x8 a1 = *reinterpret_cast<const bf16x8*>(&sQ[(16 + m16) * QPAD + ka]);
            bf16x8 b0 = *reinterpret_cast<const bf16x8*>(&sB[(wave * 32 + m16) * BPAD + kb]);
            bf16x8 b1 = *reinterpret_cast<const bf16x8*>(&sB[(wave * 32 + 16 + m16) * BPAD + kb]);
            acc[0][0] = __builtin_amdgcn_mfma_f32_16x16x32_bf16(a0, b0, acc[0][0], 0, 0, 0);
            acc[0][1] = __builtin_amdgcn_mfma_f32_16x16x32_bf16(a0, b1, acc[0][1], 0, 0, 0);
            acc[1][0] = __builtin_amdgcn_mfma_f32_16x16x32_bf16(a1, b0, acc[1][0], 0, 0, 0);
            acc[1][1] = __builtin_amdgcn_mfma_f32_16x16x32_bf16(a1, b1, acc[1][1], 0, 0, 0);
        }
    }

    // ---- norms ----
    #pragma unroll
    for (int j = 0; j < 8; ++j) atomicAdd(&s_dn2[rowbase + 16 * j], dnacc[j]);
    __syncthreads();
    if (t < QL) s_qn[t] = sqrtf(s_qn2[t]);
    if (t < BN) s_dn[t] = sqrtf(s_dn2[t]);
    __syncthreads();

    // ---- sims + histogram from C-layout: row(q)=quad*4+reg, col(d)=lane&15 ----
    int cnt[NBINS];
    #pragma unroll
    for (int k = 0; k < NBINS; ++k) cnt[k] = 0;
    #pragma unroll
    for (int mt = 0; mt < 2; ++mt) {
        #pragma unroll
        for (int nt = 0; nt < 2; ++nt) {
            int d = wave * 32 + nt * 16 + m16;
            #pragma unroll
            for (int r = 0; r < 4; ++r) {
                int q = mt * 16 + quad * 4 + r;
                if (q < QL && d < BROWS) {
                    float sim = acc[mt][nt][r] / fmaxf(s_qn[q] * s_dn[d], 1e-8f);
                    int bin = (int)floorf((sim + 1.0f) * 5.5f);  // 11 bins over [-1,1)
                    #pragma unroll
                    for (int k = 0; k < NBINS; ++k) cnt[k] += (bin == k) ? 1 : 0;
                }
            }
        }
    }
    #pragma unroll
    for (int k = 0; k < NBINS; ++k) {
        int v = cnt[k];
        for (int off = 32; off > 0; off >>= 1) v += __shfl_down(v, off, 64);
        if (lane == 0 && v != 0) atomicAdd(&s_hist[k], v);
    }
    __syncthreads();
    if (t < NBINS)
        counts[(((size_t)(l * NBATCH + b)) * DSPLIT + dc) * NBINS + t] = (float)s_hist[t];
}

// ---------------- finalize: cls dot + histogram fold + biases ----------------
__global__ __launch_bounds__(256)
void finalize_kernel(const float* __restrict__ hs,
                     const float* __restrict__ Wh,   // (5,11)
                     const float* __restrict__ bh,   // (5,)
                     const float* __restrict__ Wc,   // (1,838)
                     const float* __restrict__ bc,   // (1,)
                     const float* __restrict__ counts,
                     float* __restrict__ out) {
    const int b = blockIdx.x;
    const int t = threadIdx.x;
    float p = 0.f;

    const float* cls = hs + ((size_t)(12 * NBATCH + b)) * SS * HH;
    for (int j = t; j < HH; j += 256) p += cls[j] * Wc[j];

    if (t < 14 * NBINS) {
        const int l  = t / NBINS;             // all_layers index 0..13
        const int n  = t % NBINS;
        const int lp = (l == 0) ? 0 : l - 1;  // unique-layer index
        float hsum = 0.f;
        #pragma unroll
        for (int dcc = 0; dcc < DSPLIT; ++dcc)
            hsum += counts[(((size_t)lp * NBATCH + b) * DSPLIT + dcc) * NBINS + n];
        float hist = hsum * (1.0f / (float)(QL * DD));
        float coef = 0.f;
        #pragma unroll
        for (int o = 0; o < 5; ++o) coef += Wc[HH + l * 5 + o] * Wh[o * NBINS + n];
        p += hist * coef;
    }

    if (t == 0) {
        float s = bc[0];
        for (int l = 0; l < 14; ++l)
            for (int o = 0; o < 5; ++o) s += Wc[HH + l * 5 + o] * bh[o];
        p += s;
    }

    __shared__ float red[256];
    red[t] = p;
    __syncthreads();
    for (int off = 128; off > 0; off >>= 1) {
        if (t < off) red[t] += red[t + off];
        __syncthreads();
    }
    if (t == 0) out[b] = red[0];
}

extern "C" void kernel_launch(void* const* d_in, const int* in_sizes, int n_in,
                              void* d_out, int out_size, void* d_ws, size_t ws_size,
                              hipStream_t stream) {
    const float* hs = (const float*)d_in[0];
    const float* Wh = (const float*)d_in[1];
    const float* bh = (const float*)d_in[2];
    const float* Wc = (const float*)d_in[3];
    const float* bc = (const float*)d_in[4];
    float* counts = (float*)d_ws;      // 13*16*4*11 floats
    float* out    = (float*)d_out;     // (16,1) fp32

    dim3 g1(NLAYER, NBATCH, DSPLIT);
    gemm_hist_kernel<<<g1, 256, 0, stream>>>(hs, counts);
    finalize_kernel<<<NBATCH, 256, 0, stream>>>(hs, Wh, bh, Wc, bc, counts, out);
}